// Round 11
// baseline (831.033 us; speedup 1.0000x reference)
//
#include <hip/hip_runtime.h>
#include <cstdint>
#include <math.h>

// GREEN since r6. r9=813us, r10=829us. r10 post-mortem: NO memory scratch
// (WRITE 2368KB = exactly `out`; FETCH = weights) -> r9's "spill" is
// AGPR-resident (unified file, v_accvgpr VALU traffic). Occupancy pinned at
// 11.9% (1 wave/SIMD) across r6-r10 regardless of grid => total (VGPR+AGPR)
// allocation > 256. Culprit: fully-unrolled PROLOGUE (9x threefry gumbel loop
// = ~230 live regs) sets the whole-kernel allocation max. Steady state (r10:
// Uz/Ur regs + Un LDS) only needs ~175.
// THIS ROUND: r10 + serialized prologue (#pragma unroll 1 on keys/gumbel,
// unroll 4 on Un staging) + sched_barrier fence before U loads. Target:
// ~190 VGPR total, 2 waves/SIMD, LDS 20480 = exactly 8 blocks/CU.
// EMPIRICAL RULES: only __launch_bounds__(64,1) gives the full reg budget
// ((64,2) cuts to 128 -> r8 5912us disaster).
// Locked-in: PRNG = partitionable threefry (key_t = tf((0,42),(0,t)); bits =
// o0^o1 of tf(key_t,(0,2s+cat))); f32 in/out; out = [4096*144][4096]; decisions
// arithmetic-robust (r2/r3/r4 bit-identical; r7-r10 native-f32 absmax 0.0).

#define NSAMP 4096
#define NSTEP 144
#define HID 64
#define CPB 2            // chains per block (one wave)

typedef float v16f __attribute__((ext_vector_type(16)));

// ---- JAX threefry2x32 (20 rounds, key-inject every 4) ----
__device__ __forceinline__ void threefry2x32(uint32_t k0, uint32_t k1,
                                             uint32_t x0, uint32_t x1,
                                             uint32_t& o0, uint32_t& o1) {
  const uint32_t ks0 = k0, ks1 = k1, ks2 = k0 ^ k1 ^ 0x1BD11BDAu;
  x0 += ks0; x1 += ks1;
#define TF_ROUND(d) { x0 += x1; x1 = (x1 << (d)) | (x1 >> (32 - (d))); x1 ^= x0; }
  TF_ROUND(13) TF_ROUND(15) TF_ROUND(26) TF_ROUND(6)
  x0 += ks1; x1 += ks2 + 1u;
  TF_ROUND(17) TF_ROUND(29) TF_ROUND(16) TF_ROUND(24)
  x0 += ks2; x1 += ks0 + 2u;
  TF_ROUND(13) TF_ROUND(15) TF_ROUND(26) TF_ROUND(6)
  x0 += ks0; x1 += ks1 + 3u;
  TF_ROUND(17) TF_ROUND(29) TF_ROUND(16) TF_ROUND(24)
  x0 += ks1; x1 += ks2 + 4u;
  TF_ROUND(13) TF_ROUND(15) TF_ROUND(26) TF_ROUND(6)
  x0 += ks2; x1 += ks0 + 5u;
#undef TF_ROUND
  o0 = x0; o1 = x1;
}

__global__ __launch_bounds__(64, 1) void vmc_kernel(
    const float* __restrict__ W, const float* __restrict__ U,
    const float* __restrict__ B, const float* __restrict__ Wd,
    const float* __restrict__ Bd, float* __restrict__ out) {
#pragma clang fp contract(off)
  const int j = threadIdx.x;           // hidden unit owned by this lane
  const int s_base = blockIdx.x * CPB; // first of 2 chains in this block

  __shared__ __align__(16) float2 hsh2[HID];      // h[unit] = {chain a, chain b}
  __shared__ __align__(16) float unsh[HID * HID]; // Un [k][unit] (n-gate U)
  __shared__ uint2 kkeys[NSTEP];
  __shared__ float gsh[CPB * 2 * NSTEP];          // gumbels [c*288 + 2t + cat]

  // --- per-step keys: key_t = threefry((0,42),(0,t)) --- (serialized: no
  // register spike; one-time cost ~0.5us)
#pragma unroll 1
  for (int t = j; t < NSTEP; t += HID) {
    uint32_t o0, o1;
    threefry2x32(0u, 42u, 0u, (uint32_t)t, o0, o1);
    kkeys[t].x = o0; kkeys[t].y = o1;
  }
  // --- stage Un into LDS: unsh[k*64 + u] = U[k*192 + 128 + u] ---
#pragma unroll 4
  for (int k = 0; k < HID; ++k) unsh[k * 64 + j] = U[k * 192 + 128 + j];
  hsh2[j] = float2{0.0f, 0.0f};
  __syncthreads();

  // --- gumbels: 2 chains x 288 draws; bits = o0^o1 of tf(key_t,(0,2s+cat)).
  // SERIALIZED (unroll 1): the 9x-unrolled version software-pipelines ~230
  // live regs and that prologue spike was sizing the whole wave's allocation.
#pragma unroll 1
  for (int id = j; id < CPB * 2 * NSTEP; id += HID) {
    const int c = id / 288;
    const int idx = id - c * 288;
    const uint2 kt = kkeys[idx >> 1];
    const uint32_t i = 2u * (uint32_t)(s_base + c) + (uint32_t)(idx & 1);
    uint32_t o0, o1;
    threefry2x32(kt.x, kt.y, 0u, i, o0, o1);
    const uint32_t bits = o0 ^ o1;
    union { uint32_t u; float f; } cv; cv.u = (bits >> 9) | 0x3F800000u;
    float uf = cv.f - 1.0f;
    uf = fmaxf(uf, 1.17549435e-38f);
    const float inner = logf(uf);
    gsh[id] = -logf(-inner);
  }
  __syncthreads();
  // fence: keep the 128 U-register loads OUT of the prologue region so the
  // allocator never sees prologue-temps + U live simultaneously
  __builtin_amdgcn_sched_barrier(0);

  // --- Uz, Ur columns for unit j, register-resident (128 floats) ---
  v16f uz0, uz1, uz2, uz3, ur0, ur1, ur2, ur3;
#define LOADB(v, r, off) \
  { _Pragma("unroll") for (int e = 0; e < 16; ++e) v[e] = U[((r)*16 + e)*192 + (off) + j]; }
  LOADB(uz0, 0, 0)   LOADB(uz1, 1, 0)   LOADB(uz2, 2, 0)   LOADB(uz3, 3, 0)
  LOADB(ur0, 0, 64)  LOADB(ur1, 1, 64)  LOADB(ur2, 2, 64)  LOADB(ur3, 3, 64)
#undef LOADB

  const float b1z = B[192 + j], b1r = B[256 + j], b1n = B[320 + j];
  const float b0z = B[j],       b0r = B[64 + j],  b0n = B[128 + j];
  const float xW0z = W[j]       + b0z, xW1z = W[192 + j] + b0z;
  const float xW0r = W[64 + j]  + b0r, xW1r = W[256 + j] + b0r;
  const float xW0n = W[128 + j] + b0n, xW1n = W[320 + j] + b0n;
  const float wd0 = Wd[2*j], wd1 = Wd[2*j + 1];
  const float bd0 = Bd[0],   bd1 = Bd[1];

  float ha = 0.0f, hb_ = 0.0f;          // h for chain a / b (unit j)
  float logPa = 0.0f, logPb = 0.0f;
  float axz = b0z, axr = b0r, axn = b0n;  // chain a x-path (t=0: x=0 -> b[0])
  float bxz = b0z, bxr = b0r, bxn = b0n;  // chain b

  for (int t = 0; t < NSTEP; ++t) {
    // ---- hm = h@U (k-ascending f32 FMA from 0), both chains; z,r from
    // registers, n from LDS (same values, same order -> bit-identical) ----
    float hza = 0.f, hzb = 0.f, hra = 0.f, hrb = 0.f, hna = 0.f, hnb = 0.f;
#define DOTB(uzv, urv, base) \
    { _Pragma("unroll") for (int e = 0; e < 16; e += 2) { \
        const float4 hv = *(const float4*)&hsh2[(base) + e]; \
        const float un0 = unsh[((base) + e) * 64 + j]; \
        const float un1 = unsh[((base) + e + 1) * 64 + j]; \
        hza = __builtin_fmaf(hv.x, uzv[e],   hza); hzb = __builtin_fmaf(hv.y, uzv[e],   hzb); \
        hra = __builtin_fmaf(hv.x, urv[e],   hra); hrb = __builtin_fmaf(hv.y, urv[e],   hrb); \
        hna = __builtin_fmaf(hv.x, un0,      hna); hnb = __builtin_fmaf(hv.y, un0,      hnb); \
        hza = __builtin_fmaf(hv.z, uzv[e+1], hza); hzb = __builtin_fmaf(hv.w, uzv[e+1], hzb); \
        hra = __builtin_fmaf(hv.z, urv[e+1], hra); hrb = __builtin_fmaf(hv.w, urv[e+1], hrb); \
        hna = __builtin_fmaf(hv.z, un1,      hna); hnb = __builtin_fmaf(hv.w, un1,      hnb); } }
    DOTB(uz0, ur0, 0)
    DOTB(uz1, ur1, 16)
    DOTB(uz2, ur2, 32)
    DOTB(uz3, ur3, 48)
#undef DOTB

    // ---- gates (native f32), r7 expression order ----
    {
      const float tz = hza + b1z, tr = hra + b1r, tn = hna + b1n;
      const float az = axz + tz, ar = axr + tr;
      const float zz = __builtin_amdgcn_rcpf(1.0f + expf(-az));
      const float rr = __builtin_amdgcn_rcpf(1.0f + expf(-ar));
      const float hh = tanhf(axn + (rr * tn));
      ha = (zz * ha) + ((1.0f - zz) * hh);
    }
    {
      const float tz = hzb + b1z, tr = hrb + b1r, tn = hnb + b1n;
      const float az = bxz + tz, ar = bxr + tr;
      const float zz = __builtin_amdgcn_rcpf(1.0f + expf(-az));
      const float rr = __builtin_amdgcn_rcpf(1.0f + expf(-ar));
      const float hh = tanhf(bxn + (rr * tn));
      hb_ = (zz * hb_) + ((1.0f - zz) * hh);
    }

    hsh2[j] = float2{ha, hb_};   // for next step's DOT (single wave: ordered)

    // ---- dense h@Wd: butterfly reduction (proven decision-safe r2-vs-r4) ----
    float pa0 = ha * wd0,  pa1 = ha * wd1;    // chain a logits
    float pb0 = hb_ * wd0, pb1 = hb_ * wd1;   // chain b logits
#pragma unroll
    for (int m = 1; m < 64; m <<= 1) {
      pa0 += __shfl_xor(pa0, m, 64);
      pa1 += __shfl_xor(pa1, m, 64);
      pb0 += __shfl_xor(pb0, m, 64);
      pb1 += __shfl_xor(pb1, m, 64);
    }

    // ---- softmax + gumbel argmax + logP, per chain ----
    int sma, smb;
    {
      const float l0 = pa0 + bd0, l1 = pa1 + bd1;
      const float mxv = fmaxf(l0, l1);
      const float e0 = expf(l0 - mxv), e1 = expf(l1 - mxv);
      const float rs = __builtin_amdgcn_rcpf(e0 + e1);
      const float lp0 = logf(1e-10f + (e0 * rs));
      const float lp1 = logf(1e-10f + (e1 * rs));
      const float g0 = gsh[2*t], g1 = gsh[2*t + 1];
      sma = (lp1 + g1) > (lp0 + g0);
      logPa = logPa + (sma ? lp1 : lp0);
      axz = sma ? xW1z : xW0z;
      axr = sma ? xW1r : xW0r;
      axn = sma ? xW1n : xW0n;
    }
    {
      const float l0 = pb0 + bd0, l1 = pb1 + bd1;
      const float mxv = fmaxf(l0, l1);
      const float e0 = expf(l0 - mxv), e1 = expf(l1 - mxv);
      const float rs = __builtin_amdgcn_rcpf(e0 + e1);
      const float lp0 = logf(1e-10f + (e0 * rs));
      const float lp1 = logf(1e-10f + (e1 * rs));
      const float g0 = gsh[288 + 2*t], g1 = gsh[288 + 2*t + 1];
      smb = (lp1 + g1) > (lp0 + g0);
      logPb = logPb + (smb ? lp1 : lp0);
      bxz = smb ? xW1z : xW0z;
      bxr = smb ? xW1r : xW0r;
      bxn = smb ? xW1n : xW0n;
    }

    if (j == 0) {
      out[(s_base + 0) * NSTEP + t] = sma ? 1.0f : 0.0f;
      out[(s_base + 1) * NSTEP + t] = smb ? 1.0f : 0.0f;
    }
  }

  if (j == 0) {
    *(float2*)&out[NSAMP * NSTEP + s_base] = float2{logPa, logPb};
  }
}

extern "C" void kernel_launch(void* const* d_in, const int* in_sizes, int n_in,
                              void* d_out, int out_size, void* d_ws, size_t ws_size,
                              hipStream_t stream) {
  // inputs (setup_inputs order): nsamples(1), W(2x192), U(64x192), b(2x192),
  // Wd(64x2), bd(2) — float32
  const float* W  = (const float*)d_in[1];
  const float* U  = (const float*)d_in[2];
  const float* B  = (const float*)d_in[3];
  const float* Wd = (const float*)d_in[4];
  const float* Bd = (const float*)d_in[5];
  vmc_kernel<<<dim3(NSAMP / CPB), dim3(HID), 0, stream>>>(W, U, B, Wd, Bd, (float*)d_out);
}

// Round 12
// 529.071 us; speedup vs baseline: 1.5707x; 1.5707x over previous
//
#include <hip/hip_runtime.h>
#include <cstdint>
#include <math.h>

// GREEN since r6. r9=813, r10=829, r11=831us. r11 falsified the prologue-spike
// theory (serialized prologue: VGPR still 180, occ still 11.8). Revised model
// fitting ALL counters: 180 VGPR => 2 waves/SIMD already resident
// (OccupancyPercent is a gfx94x-formula fallback, not trustworthy); wall =
// ~6.9k cyc/SIMD-step, of which ~3.4k VALU-issued (VALUBusy 50%) -- and ~half
// that VALU is ocml libm (expf~25/tanhf~35/logf~25 instr, ~10 calls/step).
// Rest = DS latency + dep-chain stalls.
// THIS ROUND: (1) hot-loop transcendentals -> raw HW ops (__expf/__logf/
// tanh=1-2*rcp(exp(2x)+1), branch-free, correct saturation); gumbel prologue
// keeps exact f64 path. (2) software-pipeline: dot(t+1) only needs h_t, so
// tail (butterfly/softmax/sample) and next-dot share one BB -> scheduler
// fills DS latency with FMAs. (3) allow contraction (r2 ran contracted,
// decisions bit-identical). Perturbation-safety: 4 independent ulp-level
// arithmetic variants (r2 f32-libm-butterfly / r3 f64 / r4 cr-f32 / r7
// native+rcp) all produced bit-identical decision streams.
// EMPIRICAL RULES: only __launch_bounds__(64,1) gives the full reg budget.
// Locked-in: PRNG = partitionable threefry (key_t = tf((0,42),(0,t)); bits =
// o0^o1 of tf(key_t,(0,2s+cat))); f32 in/out; out = [4096*144][4096].

#define NSAMP 4096
#define NSTEP 144
#define HID 64
#define CPB 2            // chains per block (one wave)

typedef float v16f __attribute__((ext_vector_type(16)));

// ---- JAX threefry2x32 (20 rounds, key-inject every 4) ----
__device__ __forceinline__ void threefry2x32(uint32_t k0, uint32_t k1,
                                             uint32_t x0, uint32_t x1,
                                             uint32_t& o0, uint32_t& o1) {
  const uint32_t ks0 = k0, ks1 = k1, ks2 = k0 ^ k1 ^ 0x1BD11BDAu;
  x0 += ks0; x1 += ks1;
#define TF_ROUND(d) { x0 += x1; x1 = (x1 << (d)) | (x1 >> (32 - (d))); x1 ^= x0; }
  TF_ROUND(13) TF_ROUND(15) TF_ROUND(26) TF_ROUND(6)
  x0 += ks1; x1 += ks2 + 1u;
  TF_ROUND(17) TF_ROUND(29) TF_ROUND(16) TF_ROUND(24)
  x0 += ks2; x1 += ks0 + 2u;
  TF_ROUND(13) TF_ROUND(15) TF_ROUND(26) TF_ROUND(6)
  x0 += ks0; x1 += ks1 + 3u;
  TF_ROUND(17) TF_ROUND(29) TF_ROUND(16) TF_ROUND(24)
  x0 += ks1; x1 += ks2 + 4u;
  TF_ROUND(13) TF_ROUND(15) TF_ROUND(26) TF_ROUND(6)
  x0 += ks2; x1 += ks0 + 5u;
#undef TF_ROUND
  o0 = x0; o1 = x1;
}

// fast branch-free f32 transcendentals (raw v_exp_f32 / v_log_f32 / v_rcp_f32)
__device__ __forceinline__ float fsig(float x) {        // 1/(1+e^-x)
  return __builtin_amdgcn_rcpf(1.0f + __expf(-x));
}
__device__ __forceinline__ float ftanh(float x) {       // 1 - 2/(e^2x+1)
  const float e = __expf(2.0f * x);                     // inf/0 saturate to +-1
  return 1.0f - 2.0f * __builtin_amdgcn_rcpf(e + 1.0f);
}

__global__ __launch_bounds__(64, 1) void vmc_kernel(
    const float* __restrict__ W, const float* __restrict__ U,
    const float* __restrict__ B, const float* __restrict__ Wd,
    const float* __restrict__ Bd, float* __restrict__ out) {
  const int j = threadIdx.x;           // hidden unit owned by this lane
  const int s_base = blockIdx.x * CPB; // first of 2 chains in this block

  __shared__ __align__(16) float2 hsh2[HID];      // h[unit] = {chain a, chain b}
  __shared__ __align__(16) float unsh[HID * HID]; // Un [k][unit] (n-gate U)
  __shared__ uint2 kkeys[NSTEP];
  __shared__ float gsh[CPB * 2 * NSTEP];          // gumbels [c*288 + 2t + cat]

  // --- per-step keys: key_t = threefry((0,42),(0,t)) ---
#pragma unroll 1
  for (int t = j; t < NSTEP; t += HID) {
    uint32_t o0, o1;
    threefry2x32(0u, 42u, 0u, (uint32_t)t, o0, o1);
    kkeys[t].x = o0; kkeys[t].y = o1;
  }
  // --- stage Un into LDS: unsh[k*64 + u] = U[k*192 + 128 + u] ---
#pragma unroll 4
  for (int k = 0; k < HID; ++k) unsh[k * 64 + j] = U[k * 192 + 128 + j];
  hsh2[j] = float2{0.0f, 0.0f};
  __syncthreads();

  // --- gumbels: EXACT path kept (f64 libm, one-time): bits = o0^o1 of
  // tf(key_t,(0,2s+cat)); u = bitcast(bits>>9|0x3f800000)-1 clamped tiny ---
#pragma unroll 1
  for (int id = j; id < CPB * 2 * NSTEP; id += HID) {
    const int c = id / 288;
    const int idx = id - c * 288;
    const uint2 kt = kkeys[idx >> 1];
    const uint32_t i = 2u * (uint32_t)(s_base + c) + (uint32_t)(idx & 1);
    uint32_t o0, o1;
    threefry2x32(kt.x, kt.y, 0u, i, o0, o1);
    const uint32_t bits = o0 ^ o1;
    union { uint32_t u; float f; } cv; cv.u = (bits >> 9) | 0x3F800000u;
    float uf = cv.f - 1.0f;
    uf = fmaxf(uf, 1.17549435e-38f);
    const float inner = (float)log((double)uf);
    gsh[id] = -(float)log((double)(-inner));
  }
  __syncthreads();

  // --- Uz, Ur columns for unit j, register-resident (128 floats) ---
  v16f uz0, uz1, uz2, uz3, ur0, ur1, ur2, ur3;
#define LOADB(v, r, off) \
  { _Pragma("unroll") for (int e = 0; e < 16; ++e) v[e] = U[((r)*16 + e)*192 + (off) + j]; }
  LOADB(uz0, 0, 0)   LOADB(uz1, 1, 0)   LOADB(uz2, 2, 0)   LOADB(uz3, 3, 0)
  LOADB(ur0, 0, 64)  LOADB(ur1, 1, 64)  LOADB(ur2, 2, 64)  LOADB(ur3, 3, 64)
#undef LOADB

  const float b1z = B[192 + j], b1r = B[256 + j], b1n = B[320 + j];
  const float b0z = B[j],       b0r = B[64 + j],  b0n = B[128 + j];
  const float xW0z = W[j]       + b0z, xW1z = W[192 + j] + b0z;
  const float xW0r = W[64 + j]  + b0r, xW1r = W[256 + j] + b0r;
  const float xW0n = W[128 + j] + b0n, xW1n = W[320 + j] + b0n;
  const float wd0 = Wd[2*j], wd1 = Wd[2*j + 1];
  const float bd0 = Bd[0],   bd1 = Bd[1];

  float ha = 0.0f, hb_ = 0.0f;
  float logPa = 0.0f, logPb = 0.0f;
  float axz = b0z, axr = b0r, axn = b0n;  // t=0: x=0 -> xm = b[0]
  float bxz = b0z, bxr = b0r, bxn = b0n;
  // loop-carried dot accumulators; h_{-1}=0 -> dot=0 for t=0
  float hza = 0.f, hzb = 0.f, hra = 0.f, hrb = 0.f, hna = 0.f, hnb = 0.f;

  for (int t = 0; t < NSTEP; ++t) {
    // ---- gates from the PREVIOUS iteration's dot (software pipeline) ----
    {
      const float az = axz + (hza + b1z), ar = axr + (hra + b1r);
      const float zz = fsig(az), rr = fsig(ar);
      const float hh = ftanh(axn + rr * (hna + b1n));
      ha = zz * ha + (1.0f - zz) * hh;
    }
    {
      const float az = bxz + (hzb + b1z), ar = bxr + (hrb + b1r);
      const float zz = fsig(az), rr = fsig(ar);
      const float hh = ftanh(bxn + rr * (hnb + b1n));
      hb_ = zz * hb_ + (1.0f - zz) * hh;
    }
    hsh2[j] = float2{ha, hb_};   // single wave: LDS ops in program order

    // ---- tail: butterfly dense + softmax + gumbel sample (indep. of dot) ----
    float pa0 = ha * wd0,  pa1 = ha * wd1;
    float pb0 = hb_ * wd0, pb1 = hb_ * wd1;
#pragma unroll
    for (int m = 1; m < 64; m <<= 1) {
      pa0 += __shfl_xor(pa0, m, 64);
      pa1 += __shfl_xor(pa1, m, 64);
      pb0 += __shfl_xor(pb0, m, 64);
      pb1 += __shfl_xor(pb1, m, 64);
    }
    int sma, smb;
    {
      const float l0 = pa0 + bd0, l1 = pa1 + bd1;
      const float mxv = fmaxf(l0, l1);
      const float e0 = __expf(l0 - mxv), e1 = __expf(l1 - mxv);
      const float rs = __builtin_amdgcn_rcpf(e0 + e1);
      const float lp0 = __logf(1e-10f + e0 * rs);
      const float lp1 = __logf(1e-10f + e1 * rs);
      const float g0 = gsh[2*t], g1 = gsh[2*t + 1];
      sma = (lp1 + g1) > (lp0 + g0);
      logPa += sma ? lp1 : lp0;
      axz = sma ? xW1z : xW0z;
      axr = sma ? xW1r : xW0r;
      axn = sma ? xW1n : xW0n;
    }
    {
      const float l0 = pb0 + bd0, l1 = pb1 + bd1;
      const float mxv = fmaxf(l0, l1);
      const float e0 = __expf(l0 - mxv), e1 = __expf(l1 - mxv);
      const float rs = __builtin_amdgcn_rcpf(e0 + e1);
      const float lp0 = __logf(1e-10f + e0 * rs);
      const float lp1 = __logf(1e-10f + e1 * rs);
      const float g0 = gsh[288 + 2*t], g1 = gsh[288 + 2*t + 1];
      smb = (lp1 + g1) > (lp0 + g0);
      logPb += smb ? lp1 : lp0;
      bxz = smb ? xW1z : xW0z;
      bxr = smb ? xW1r : xW0r;
      bxn = smb ? xW1n : xW0n;
    }
    if (j == 0) {
      out[(s_base + 0) * NSTEP + t] = sma ? 1.0f : 0.0f;
      out[(s_base + 1) * NSTEP + t] = smb ? 1.0f : 0.0f;
    }

    // ---- dot for NEXT step: hm = h_t @ U (k-ascending FMA from 0); only
    // needs h_t (in LDS), not the sample -> overlaps the tail above ----
    hza = 0.f; hzb = 0.f; hra = 0.f; hrb = 0.f; hna = 0.f; hnb = 0.f;
#define DOTB(uzv, urv, base) \
    { _Pragma("unroll") for (int e = 0; e < 16; e += 2) { \
        const float4 hv = *(const float4*)&hsh2[(base) + e]; \
        const float un0 = unsh[((base) + e) * 64 + j]; \
        const float un1 = unsh[((base) + e + 1) * 64 + j]; \
        hza = __builtin_fmaf(hv.x, uzv[e],   hza); hzb = __builtin_fmaf(hv.y, uzv[e],   hzb); \
        hra = __builtin_fmaf(hv.x, urv[e],   hra); hrb = __builtin_fmaf(hv.y, urv[e],   hrb); \
        hna = __builtin_fmaf(hv.x, un0,      hna); hnb = __builtin_fmaf(hv.y, un0,      hnb); \
        hza = __builtin_fmaf(hv.z, uzv[e+1], hza); hzb = __builtin_fmaf(hv.w, uzv[e+1], hzb); \
        hra = __builtin_fmaf(hv.z, urv[e+1], hra); hrb = __builtin_fmaf(hv.w, urv[e+1], hrb); \
        hna = __builtin_fmaf(hv.z, un1,      hna); hnb = __builtin_fmaf(hv.w, un1,      hnb); } }
    DOTB(uz0, ur0, 0)
    DOTB(uz1, ur1, 16)
    DOTB(uz2, ur2, 32)
    DOTB(uz3, ur3, 48)
#undef DOTB
  }

  if (j == 0) {
    *(float2*)&out[NSAMP * NSTEP + s_base] = float2{logPa, logPb};
  }
}

extern "C" void kernel_launch(void* const* d_in, const int* in_sizes, int n_in,
                              void* d_out, int out_size, void* d_ws, size_t ws_size,
                              hipStream_t stream) {
  // inputs (setup_inputs order): nsamples(1), W(2x192), U(64x192), b(2x192),
  // Wd(64x2), bd(2) — float32
  const float* W  = (const float*)d_in[1];
  const float* U  = (const float*)d_in[2];
  const float* B  = (const float*)d_in[3];
  const float* Wd = (const float*)d_in[4];
  const float* Bd = (const float*)d_in[5];
  vmc_kernel<<<dim3(NSAMP / CPB), dim3(HID), 0, stream>>>(W, U, B, Wd, Bd, (float*)d_out);
}